// Round 4
// baseline (1574.634 us; speedup 1.0000x reference)
//
#include <hip/hip_runtime.h>
#include <math.h>

#define LRELU(x) ((x) > 0.0f ? (x) : 0.01f * (x))

typedef __attribute__((ext_vector_type(8))) short short8;
typedef __attribute__((ext_vector_type(4))) float f32x4;

__device__ __forceinline__ unsigned fenc(float f) {
    unsigned u = __float_as_uint(f);
    return (u & 0x80000000u) ? ~u : (u | 0x80000000u);
}
__device__ __forceinline__ float fdec(unsigned u) {
    return __uint_as_float((u & 0x80000000u) ? (u & 0x7FFFFFFFu) : ~u);
}
__device__ __forceinline__ unsigned short f2bf(float f) {
    unsigned u = __float_as_uint(f);
    u += 0x7FFFu + ((u >> 16) & 1u);
    return (unsigned short)(u >> 16);
}
__device__ __forceinline__ float bf2f(unsigned short b) {
    return __uint_as_float(((unsigned)b) << 16);
}
__device__ __forceinline__ ushort4 cvt4(float4 v) {
    ushort4 p;
    p.x = f2bf(v.x); p.y = f2bf(v.y); p.z = f2bf(v.z); p.w = f2bf(v.w);
    return p;
}

// ---- all 8 weight matrices -> one contiguous bf16 arena, single launch ----
__global__ __launch_bounds__(256) void wcvt_k(
    const float* __restrict__ s0, const float* __restrict__ s1,
    const float* __restrict__ s2, const float* __restrict__ s3,
    const float* __restrict__ s4, const float* __restrict__ s5,
    const float* __restrict__ s6, const float* __restrict__ s7,
    unsigned short* __restrict__ dst)
{
    long long e = ((long long)blockIdx.x * 256 + threadIdx.x) * 4;
    if (e >= 327680) return;
    int c = (int)(e >> 15);
    const float* s;
    long long off = e & 32767;
    switch (c) {
        case 0: s = s0; break;
        case 1: s = s1; break;
        case 2: s = s2; break;
        case 3: s = s3; break;
        case 4: s = s4; break;
        case 5: s = s5; break;
        case 6: s = s6; break;
        case 7: s = s6; off += 32768; break;
        case 8: s = s7; break;
        default: s = s7; off += 32768; break;
    }
    float4 v = *(const float4*)&s[off];
    *(ushort4*)&dst[e] = cvt4(v);
}

// ---- fp32 -> bf16 streaming convert (m_feats) ----
__global__ __launch_bounds__(256) void cvt1_k(
    const float* __restrict__ in, unsigned short* __restrict__ out, int n4)
{
    int stride = gridDim.x * 256;
    for (int u = blockIdx.x * 256 + threadIdx.x; u < n4; u += stride) {
        float4 v = *(const float4*)&in[(size_t)u * 4];
        *(ushort4*)&out[(size_t)u * 4] = cvt4(v);
    }
}

// stage a 64-row x 128-col A tile into smem at ushort stride 136 (coalesced,
// issue-all-loads-then-convert). Returns having written rows [0,64) of tile.
__device__ __forceinline__ void stage_A128(
    unsigned short* __restrict__ smem, const void* __restrict__ Av, int is_bf16,
    int row0, int M, int tid, int col_off, int stride)
{
    if (is_bf16) {
        const unsigned short* A = (const unsigned short*)Av;
        short8 v[4];
#pragma unroll
        for (int k = 0; k < 4; ++k) {
            int j = tid + k * 256;
            int r = row0 + (j >> 4);
#pragma unroll
            for (int q = 0; q < 8; ++q) v[k][q] = 0;
            if (r < M) v[k] = *(const short8*)&A[(size_t)r * 128 + (j & 15) * 8];
        }
#pragma unroll
        for (int k = 0; k < 4; ++k) {
            int j = tid + k * 256;
            *(short8*)&smem[(j >> 4) * stride + col_off + (j & 15) * 8] = v[k];
        }
    } else {
        const float* A = (const float*)Av;
        float4 va[8];
#pragma unroll
        for (int k = 0; k < 8; ++k) {
            int i = tid + k * 256;
            int r = row0 + (i >> 5);
            va[k] = make_float4(0.f, 0.f, 0.f, 0.f);
            if (r < M) va[k] = *(const float4*)&A[(size_t)r * 128 + (i & 31) * 4];
        }
#pragma unroll
        for (int k = 0; k < 8; ++k) {
            int i = tid + k * 256;
            *(ushort4*)&smem[(i >> 5) * stride + col_off + (i & 31) * 4] = cvt4(va[k]);
        }
    }
}

// ============ dual MFMA GEMM: C1,C2[M,256](bf16) = A[M,128] @ W[512,128]^T ============
// staged-LDS A; A-frags hoisted to regs so the C stash can reuse the LDS buffer
// and both W-passes share one staged A.
__global__ __launch_bounds__(256) void gemm128_dual(
    const void* __restrict__ Av, int a_is_bf16,
    const unsigned short* __restrict__ Wbf,
    unsigned short* __restrict__ C1, unsigned short* __restrict__ C2, int M)
{
    __shared__ __align__(16) unsigned short smem[64 * 264];
    const int tid = threadIdx.x;
    const int wv = tid >> 6, lane = tid & 63;
    const int ln = lane & 15, quad = lane >> 4;
    const int row0 = blockIdx.x * 64;

    stage_A128(smem, Av, a_is_bf16, row0, M, tid, 0, 136);
    __syncthreads();

    short8 a[4];
#pragma unroll
    for (int ks = 0; ks < 4; ++ks)
        a[ks] = *(const short8*)&smem[(wv * 16 + ln) * 136 + ks * 32 + quad * 8];
    __syncthreads();  // all a-regs loaded before any wave's stash overwrites

#pragma unroll 1
    for (int h = 0; h < 2; ++h) {
        f32x4 acc[16];
#pragma unroll
        for (int t = 0; t < 16; ++t) acc[t] = (f32x4){0.f, 0.f, 0.f, 0.f};
        const unsigned short* W = Wbf + (size_t)h * 256 * 128;
#pragma unroll
        for (int ks = 0; ks < 4; ++ks) {
#pragma unroll
            for (int t = 0; t < 16; ++t) {
                short8 b = *(const short8*)&W[(size_t)(t * 16 + ln) * 128 + ks * 32 + quad * 8];
                acc[t] = __builtin_amdgcn_mfma_f32_16x16x32_bf16(a[ks], b, acc[t], 0, 0, 0);
            }
        }
        // stash wave-own rows (no barrier: MFMA loop is register-only)
#pragma unroll
        for (int t = 0; t < 16; ++t) {
            int col = t * 16 + ln;
#pragma unroll
            for (int rg = 0; rg < 4; ++rg)
                smem[(wv * 16 + quad * 4 + rg) * 264 + col] = f2bf(acc[t][rg]);
        }
        asm volatile("" ::: "memory");
        unsigned short* C = h ? C2 : C1;
#pragma unroll
        for (int k = 0; k < 8; ++k) {
            int j = lane + k * 64;
            int row = j >> 5, c8 = (j & 31) * 8;
            int r = row0 + wv * 16 + row;
            if (r < M)
                *(short8*)&C[(size_t)r * 256 + c8] = *(const short8*)&smem[(wv * 16 + row) * 264 + c8];
        }
        asm volatile("" ::: "memory");
    }
}

// ============ fused fij MFMA GEMM + attention score ============
// staged-LDS A, hoisted a-regs; epilogue: pre-gathered fni/fnj + wave-own stash.
__global__ __launch_bounds__(256) void gemm_score_mfma(
    const void* __restrict__ Av, int a_is_bf16,
    const unsigned short* __restrict__ Wbf,
    const unsigned short* __restrict__ fni, const unsigned short* __restrict__ fnj,
    const float* __restrict__ bias, const float* __restrict__ attn,
    const int* __restrict__ src, const int* __restrict__ dst,
    float* __restrict__ ebuf, unsigned* __restrict__ smax, int M)
{
    __shared__ __align__(16) unsigned short smem[64 * 264];
    const int tid = threadIdx.x;
    const int wv = tid >> 6, lane = tid & 63;
    const int ln = lane & 15, quad = lane >> 4;
    const int row0 = blockIdx.x * 64;
    const int myr = row0 + wv * 16 + ln;

    int msrc = 0, mdst = 0;
    if (myr < M) { msrc = src[myr]; mdst = dst[myr]; }

    stage_A128(smem, Av, a_is_bf16, row0, M, tid, 0, 136);
    __syncthreads();

    short8 a[4];
#pragma unroll
    for (int ks = 0; ks < 4; ++ks)
        a[ks] = *(const short8*)&smem[(wv * 16 + ln) * 136 + ks * 32 + quad * 8];
    __syncthreads();

    f32x4 acc[16];
#pragma unroll
    for (int t = 0; t < 16; ++t) acc[t] = (f32x4){0.f, 0.f, 0.f, 0.f};
#pragma unroll
    for (int ks = 0; ks < 4; ++ks) {
#pragma unroll
        for (int t = 0; t < 16; ++t) {
            short8 b = *(const short8*)&Wbf[(size_t)(t * 16 + ln) * 128 + ks * 32 + quad * 8];
            acc[t] = __builtin_amdgcn_mfma_f32_16x16x32_bf16(a[ks], b, acc[t], 0, 0, 0);
        }
    }

    const int c4 = lane * 4;
    const float4 bias4 = *(const float4*)&bias[c4];
    const float4 attn4 = *(const float4*)&attn[c4];

    // issue ALL 32 gathers; they land while we stash fij to LDS
    ushort4 pu[16], pv[16];
#pragma unroll
    for (int j = 0; j < 16; ++j) {
        int s_ = __shfl(msrc, j, 16);
        int d_ = __shfl(mdst, j, 16);
        pu[j] = *(const ushort4*)&fni[(size_t)s_ * 256 + c4];
        pv[j] = *(const ushort4*)&fnj[(size_t)d_ * 256 + c4];
    }

    // stash fij (bf16) row-major; wave-own rows, no barrier
#pragma unroll
    for (int t = 0; t < 16; ++t) {
        int col = t * 16 + ln;
#pragma unroll
        for (int rg = 0; rg < 4; ++rg)
            smem[(wv * 16 + quad * 4 + rg) * 264 + col] = f2bf(acc[t][rg]);
    }
    asm volatile("" ::: "memory");

#pragma unroll
    for (int i = 0; i < 16; ++i) {
        int rr = wv * 16 + i;
        int r = row0 + rr;
        if (r >= M) continue;
        int dIdx = __shfl(mdst, i, 16);
        ushort4 f4 = *(const ushort4*)&smem[rr * 264 + c4];
        float v0 = bf2f(f4.x) + bf2f(pu[i].x) + bf2f(pv[i].x) + bias4.x;
        float v1 = bf2f(f4.y) + bf2f(pu[i].y) + bf2f(pv[i].y) + bias4.y;
        float v2 = bf2f(f4.z) + bf2f(pu[i].z) + bf2f(pv[i].z) + bias4.z;
        float v3 = bf2f(f4.w) + bf2f(pu[i].w) + bf2f(pv[i].w) + bias4.w;
        float p = LRELU(v0) * attn4.x + LRELU(v1) * attn4.y
                + LRELU(v2) * attn4.z + LRELU(v3) * attn4.w;
        p += __shfl_xor(p, 1, 64);
        p += __shfl_xor(p, 2, 64);
        p += __shfl_xor(p, 4, 64);
        p += __shfl_xor(p, 8, 64);
        if (ln == 0) {
            ebuf[(size_t)r * 4 + quad] = p;
            atomicMax(&smax[(size_t)dIdx * 4 + quad], fenc(p));
        }
    }
}

// ============ K=256 MFMA GEMM for h1 (mode 0) / h2 (mode 1) ============
__global__ __launch_bounds__(256) void gemm256_mfma(
    const void* __restrict__ Mv, int m_is_bf16,
    const unsigned short* __restrict__ Aux, const float* __restrict__ lf,
    const int* __restrict__ gsrc, const int* __restrict__ gdst,
    const unsigned short* __restrict__ Wbf, const float* __restrict__ biasf,
    unsigned short* __restrict__ Cout, int M, int mode)
{
    __shared__ __align__(16) unsigned short smem[64 * 264];
    const int tid = threadIdx.x;
    const int wv = tid >> 6, lane = tid & 63;
    const int ln = lane & 15, quad = lane >> 4;
    const int row0 = blockIdx.x * 64;

    if (mode == 0) {
        stage_A128(smem, Mv, m_is_bf16, row0, M, tid, 0, 264);
        stage_A128(smem, Aux, 1, row0, M, tid, 128, 264);
    } else {
        // cols 0..127: l_feats[src]+l_feats[dst] (index-prefetched, all loads in flight)
        int is[8], id[8];
#pragma unroll
        for (int k = 0; k < 8; ++k) {
            int i = tid + k * 256;
            int r = row0 + (i >> 5);
            is[k] = (r < M) ? gsrc[r] : 0;
            id[k] = (r < M) ? gdst[r] : 0;
        }
        float4 va[8], vb2[8];
#pragma unroll
        for (int k = 0; k < 8; ++k) {
            int i = tid + k * 256;
            int c4i = (i & 31) * 4;
            va[k]  = *(const float4*)&lf[(size_t)is[k] * 128 + c4i];
            vb2[k] = *(const float4*)&lf[(size_t)id[k] * 128 + c4i];
        }
#pragma unroll
        for (int k = 0; k < 8; ++k) {
            int i = tid + k * 256;
            int r = row0 + (i >> 5);
            int c4i = (i & 31) * 4;
            float4 v = make_float4(va[k].x + vb2[k].x, va[k].y + vb2[k].y,
                                   va[k].z + vb2[k].z, va[k].w + vb2[k].w);
            if (r >= M) v = make_float4(0.f, 0.f, 0.f, 0.f);
            *(ushort4*)&smem[(i >> 5) * 264 + c4i] = cvt4(v);
        }
        // cols 128..255: m_feats
        stage_A128(smem, Mv, m_is_bf16, row0, M, tid, 128, 264);
    }
    __syncthreads();

    short8 a[8];
#pragma unroll
    for (int ks = 0; ks < 8; ++ks)
        a[ks] = *(const short8*)&smem[(wv * 16 + ln) * 264 + ks * 32 + quad * 8];
    __syncthreads();

    f32x4 acc[16];
#pragma unroll
    for (int t = 0; t < 16; ++t) acc[t] = (f32x4){0.f, 0.f, 0.f, 0.f};
#pragma unroll
    for (int ks = 0; ks < 8; ++ks) {
#pragma unroll
        for (int t = 0; t < 16; ++t) {
            short8 b = *(const short8*)&Wbf[(size_t)(t * 16 + ln) * 256 + ks * 32 + quad * 8];
            acc[t] = __builtin_amdgcn_mfma_f32_16x16x32_bf16(a[ks], b, acc[t], 0, 0, 0);
        }
    }

#pragma unroll
    for (int t = 0; t < 16; ++t) {
        int col = t * 16 + ln;
        float bb = biasf[col];
#pragma unroll
        for (int rg = 0; rg < 4; ++rg)
            smem[(wv * 16 + quad * 4 + rg) * 264 + col] = f2bf(acc[t][rg] + bb);
    }
    asm volatile("" ::: "memory");
#pragma unroll
    for (int k = 0; k < 8; ++k) {
        int j = lane + k * 64;
        int row = j >> 5, c8 = (j & 31) * 8;
        int r = row0 + wv * 16 + row;
        if (r < M)
            *(short8*)&Cout[(size_t)r * 256 + c8] = *(const short8*)&smem[(wv * 16 + row) * 264 + c8];
    }
}

// ---------------- softmax pass 2 (g branch): exp(e-max), atomic denom ----------------
__global__ __launch_bounds__(256) void edge_exp(
    float* __restrict__ ebuf, const unsigned* __restrict__ smax,
    float* __restrict__ sden, const int* __restrict__ dst, int nE)
{
    int i = blockIdx.x * 256 + threadIdx.x;
    if (i >= nE * 4) return;
    int e = i >> 2, h = i & 3;
    int d = dst[e];
    float m = fdec(smax[(size_t)d * 4 + h]);
    float ex = expf(ebuf[i] - m);
    ebuf[i] = ex;
    atomicAdd(&sden[(size_t)d * 4 + h], ex);
}

// ================= CSR build over lg_dst =================
__global__ __launch_bounds__(256) void count_k(
    const int* __restrict__ dst, int* __restrict__ cnt, int n)
{
    int i = blockIdx.x * 256 + threadIdx.x;
    if (i < n) atomicAdd(&cnt[dst[i]], 1);
}

__global__ __launch_bounds__(256) void scan1(
    const int* __restrict__ cnt, int* __restrict__ excl, int* __restrict__ bsum, int n)
{
    __shared__ int sd[256];
    int tid = threadIdx.x;
    int i = blockIdx.x * 256 + tid;
    int v = (i < n) ? cnt[i] : 0;
    sd[tid] = v;
    __syncthreads();
    for (int off2 = 1; off2 < 256; off2 <<= 1) {
        int t = (tid >= off2) ? sd[tid - off2] : 0;
        __syncthreads();
        sd[tid] += t;
        __syncthreads();
    }
    if (i < n) excl[i] = sd[tid] - v;
    if (tid == 255) bsum[blockIdx.x] = sd[255];
}

__global__ __launch_bounds__(1024) void scan2(int* __restrict__ bsum, int nb)
{
    __shared__ int sd[1024];
    int tid = threadIdx.x;
    int v = (tid < nb) ? bsum[tid] : 0;
    sd[tid] = v;
    __syncthreads();
    for (int off2 = 1; off2 < 1024; off2 <<= 1) {
        int t = (tid >= off2) ? sd[tid - off2] : 0;
        __syncthreads();
        sd[tid] += t;
        __syncthreads();
    }
    if (tid < nb) bsum[tid] = sd[tid] - v;  // exclusive
}

__global__ __launch_bounds__(256) void scan3(
    int* __restrict__ excl, const int* __restrict__ bsum, int n, int total)
{
    int i = blockIdx.x * 256 + threadIdx.x;
    if (i < n) excl[i] += bsum[i >> 8];
    if (i == 0) excl[n] = total;
}

__global__ __launch_bounds__(256) void fill_k(
    const int* __restrict__ dst, const int* __restrict__ row_ptr,
    int* __restrict__ cursor, int* __restrict__ colidx, int n)
{
    int i = blockIdx.x * 256 + threadIdx.x;
    if (i >= n) return;
    int d = dst[i];
    int p = atomicAdd(&cursor[d], 1);
    colidx[row_ptr[d] + p] = i;
}

// ---------------- CSR mean-gather of x_feats onto lg_dst (bf16 out) ----------------
__global__ __launch_bounds__(256) void agg_gather(
    const int* __restrict__ row_ptr, const int* __restrict__ colidx,
    const float* __restrict__ x, unsigned short* __restrict__ aggbf, int nE)
{
    const int lane = threadIdx.x & 63;
    const int d = blockIdx.x * 4 + (threadIdx.x >> 6);
    if (d >= nE) return;
    int b = row_ptr[d], en = row_ptr[d + 1];
    float s0 = 0.f, s1 = 0.f;
    for (int k = b; k < en; ++k) {
        int e = colidx[k];
        float2 v = *(const float2*)&x[(size_t)e * 128 + lane * 2];
        s0 += v.x; s1 += v.y;
    }
    float c = fmaxf((float)(en - b), 1.0f);
    ushort2 o;
    o.x = f2bf(s0 / c); o.y = f2bf(s1 / c);
    *(ushort2*)&aggbf[(size_t)d * 128 + lane * 2] = o;
}

// ---------------- final: lg-softmax (max precomputed) + weighted gather + epilogue ----------------
__global__ __launch_bounds__(256) void final_agg(
    const int* __restrict__ row_ptr, const int* __restrict__ colidx,
    const int* __restrict__ lg_src, const float* __restrict__ e_lg,
    const unsigned* __restrict__ lgmax,
    const unsigned short* __restrict__ h1, const unsigned short* __restrict__ h2,
    const float* __restrict__ e_g, const float* __restrict__ gden,
    const int* __restrict__ g_dst, float* __restrict__ out, int nE)
{
    const int lane = threadIdx.x & 63;
    const int d = blockIdx.x * 4 + (threadIdx.x >> 6);
    if (d >= nE) return;
    int b = row_ptr[d], en = row_ptr[d + 1];

    uint4 mu = *(const uint4*)&lgmax[(size_t)d * 4];
    float mx0 = fdec(mu.x), mx1 = fdec(mu.y), mx2 = fdec(mu.z), mx3 = fdec(mu.w);

    float den0 = 0.f, den1 = 0.f, den2 = 0.f, den3 = 0.f;
    float a10 = 0.f, a11 = 0.f, a12 = 0.f, a13 = 0.f;
    float a20 = 0.f, a21 = 0.f, a22 = 0.f, a23 = 0.f;
    for (int k = b; k < en; ++k) {
        int e = colidx[k];
        float4 sc = *(const float4*)&e_lg[(size_t)e * 4];
        float w0 = expf(sc.x - mx0), w1 = expf(sc.y - mx1);
        float w2 = expf(sc.z - mx2), w3 = expf(sc.w - mx3);
        den0 += w0; den1 += w1; den2 += w2; den3 += w3;
        int s = lg_src[e];
        const unsigned short* p1 = &h1[(size_t)s * 256 + lane];
        const unsigned short* p2 = &h2[(size_t)s * 256 + lane];
        a10 += bf2f(p1[0])   * w0;
        a11 += bf2f(p1[64])  * w1;
        a12 += bf2f(p1[128]) * w2;
        a13 += bf2f(p1[192]) * w3;
        a20 += bf2f(p2[0]);
        a21 += bf2f(p2[64]);
        a22 += bf2f(p2[128]);
        a23 += bf2f(p2[192]);
    }
    float o = 0.f;
    if (en > b) {
        float v0 = a10 / den0, v1 = a11 / den1, v2 = a12 / den2, v3 = a13 / den3;
        o += LRELU(v0) + LRELU(v1) + LRELU(v2) + LRELU(v3);
    }
    int gd = g_dst[d];
    float g0 = e_g[(size_t)d * 4 + 0] / gden[(size_t)gd * 4 + 0] * a20;
    float g1 = e_g[(size_t)d * 4 + 1] / gden[(size_t)gd * 4 + 1] * a21;
    float g2 = e_g[(size_t)d * 4 + 2] / gden[(size_t)gd * 4 + 2] * a22;
    float g3 = e_g[(size_t)d * 4 + 3] / gden[(size_t)gd * 4 + 3] * a23;
    o += LRELU(g0) + LRELU(g1) + LRELU(g2) + LRELU(g3);
    out[(size_t)d * 64 + lane] = o;
}

extern "C" void kernel_launch(void* const* d_in, const int* in_sizes, int n_in,
                              void* d_out, int out_size, void* d_ws, size_t ws_size,
                              hipStream_t stream)
{
    const float* l_feats   = (const float*)d_in[0];
    const float* m_feats   = (const float*)d_in[1];
    const float* x_feats   = (const float*)d_in[2];
    const int*   g_src     = (const int*)d_in[3];
    const int*   g_dst     = (const int*)d_in[4];
    const int*   lg_src    = (const int*)d_in[5];
    const int*   lg_dst    = (const int*)d_in[6];
    const float* W_lg_node = (const float*)d_in[7];
    const float* b_lg_node = (const float*)d_in[8];
    const float* W_lg_ni   = (const float*)d_in[9];
    const float* W_lg_fij  = (const float*)d_in[10];
    const float* W_lg_nj   = (const float*)d_in[11];
    const float* lg_attn   = (const float*)d_in[12];
    const float* bias_lg   = (const float*)d_in[13];
    const float* W_g_node  = (const float*)d_in[14];
    const float* b_g_node  = (const float*)d_in[15];
    const float* W_g_ni    = (const float*)d_in[16];
    const float* W_g_fij   = (const float*)d_in[17];
    const float* W_g_nj    = (const float*)d_in[18];
    const float* g_attn    = (const float*)d_in[19];
    const float* bias_g    = (const float*)d_in[20];

    const int N  = in_sizes[0] / 128;
    const int E  = in_sizes[3];
    const int E2 = in_sizes[5];

    float* ws = (float*)d_ws;
    size_t off = 0;
    auto alloc = [&](size_t n) { float* p = ws + off; off += n; return p; };

    // bf16 weights arena (ushort offsets within a float-slot arena)
    unsigned short* wbuf = (unsigned short*)alloc(163840);
    unsigned short* wgni_pair  = wbuf;                 // [512,128]: wgni|wgnj
    unsigned short* wlgni_pair = wbuf + 65536;         // [512,128]: wlgni|wlgnj
    unsigned short* wlgfij_bf  = wbuf + 131072;
    unsigned short* wgfij_bf   = wbuf + 163840;
    unsigned short* wlgnode_bf = wbuf + 196608;
    unsigned short* wgnode_bf  = wbuf + 262144;

    unsigned short* ni_lg = (unsigned short*)alloc((size_t)E * 128);  // [E,256] bf16 -> h1
    unsigned short* nj_lg = (unsigned short*)alloc((size_t)E * 128);  // [E,256] bf16 -> h2
    unsigned short* gni   = (unsigned short*)alloc((size_t)N * 128);
    unsigned short* gnj   = (unsigned short*)alloc((size_t)N * 128);
    unsigned short* aggbf = (unsigned short*)alloc((size_t)E * 64);   // [E,128] bf16
    float* e_lg  = alloc((size_t)E2 * 4);                             // raw lg scores
    float* e_g   = alloc((size_t)E * 4);                              // raw -> exp g scores
    unsigned* gmax = (unsigned*)alloc((size_t)N * 4);
    float* gden  = alloc((size_t)N * 4);
    unsigned* lgmax = (unsigned*)alloc((size_t)E * 4);                // lg segment max (fenc)
    int* row_ptr = (int*)alloc((size_t)E + 4);
    int* colidx  = (int*)alloc((size_t)E2);
    int* cnt     = (int*)alloc((size_t)E);
    int* cursor  = (int*)alloc((size_t)E);
    int* bsum    = (int*)alloc(1024);

    // mbf allocated LAST and only if it fits in the workspace (ws overflow guard)
    const int use_mbf = ((off + (size_t)E * 64) * sizeof(float) <= ws_size) ? 1 : 0;
    unsigned short* mbf = use_mbf ? (unsigned short*)alloc((size_t)E * 64) : nullptr;
    const void* mA = use_mbf ? (const void*)mbf : (const void*)m_feats;

    unsigned short* h1 = ni_lg;
    unsigned short* h2 = nj_lg;

    (void)n_in; (void)out_size;
    float* outp = (float*)d_out;
    dim3 blk(256);

    hipMemsetAsync(cnt,    0, (size_t)E * 4, stream);
    hipMemsetAsync(cursor, 0, (size_t)E * 4, stream);
    hipMemsetAsync(gmax,   0, (size_t)N * 4 * 4, stream);
    hipMemsetAsync(gden,   0, (size_t)N * 4 * 4, stream);
    hipMemsetAsync(lgmax,  0, (size_t)E * 4 * 4, stream);

    // all weights -> bf16 arena (one launch); m_feats -> bf16 if space permits
    wcvt_k<<<320, blk, 0, stream>>>(W_g_ni, W_g_nj, W_lg_ni, W_lg_nj,
                                    W_lg_fij, W_g_fij, W_lg_node, W_g_node, wbuf);
    if (use_mbf)
        cvt1_k<<<2048, blk, 0, stream>>>(m_feats, mbf, E * 32);

    // CSR over lg_dst
    const int nb = (E + 255) / 256;
    count_k<<<(E2 + 255) / 256, blk, 0, stream>>>(lg_dst, cnt, E2);
    scan1<<<nb, blk, 0, stream>>>(cnt, row_ptr, bsum, E);
    scan2<<<1, 1024, 0, stream>>>(bsum, nb);
    scan3<<<nb, blk, 0, stream>>>(row_ptr, bsum, E, E2);
    fill_k<<<(E2 + 255) / 256, blk, 0, stream>>>(lg_dst, row_ptr, cursor, colidx, E2);

    // projection GEMMs: dual-output, shared A (K=128 -> 2x256 cols, bf16 out)
    gemm128_dual<<<(N + 63) / 64, blk, 0, stream>>>(l_feats, 0, wgni_pair, gni, gnj, N);
    gemm128_dual<<<(E + 63) / 64, blk, 0, stream>>>(mA, use_mbf, wlgni_pair, ni_lg, nj_lg, E);

    // fused fij GEMM + raw scores (+ segment max for both branches)
    gemm_score_mfma<<<(E2 + 63) / 64, blk, 0, stream>>>(
        x_feats, 0, wlgfij_bf, ni_lg, nj_lg, bias_lg, lg_attn, lg_src, lg_dst,
        e_lg, lgmax, E2);
    gemm_score_mfma<<<(E + 63) / 64, blk, 0, stream>>>(
        mA, use_mbf, wgfij_bf, gni, gnj, bias_g, g_attn, g_src, g_dst,
        e_g, gmax, E);

    // g softmax pass 2 (exp + denom)
    edge_exp<<<(unsigned)(((long long)E * 4 + 255) / 256), blk, 0, stream>>>(e_g, gmax, gden, g_dst, E);

    // CSR mean-gather of x_feats -> aggbf (fp32 input for accuracy)
    agg_gather<<<(E + 3) / 4, blk, 0, stream>>>(row_ptr, colidx, x_feats, aggbf, E);

    // node-update GEMMs (overwrite ni_lg/nj_lg -> h1/h2; safe after gemm_score)
    gemm256_mfma<<<(E + 63) / 64, blk, 0, stream>>>(
        mA, use_mbf, aggbf, nullptr, nullptr, nullptr, wlgnode_bf, b_lg_node, h1, E, 0);
    gemm256_mfma<<<(E + 63) / 64, blk, 0, stream>>>(
        mA, use_mbf, nullptr, l_feats, g_src, g_dst, wgnode_bf, b_g_node, h2, E, 1);

    // final: lg softmax (max precomputed) + weighted gathers + epilogue
    final_agg<<<(E + 3) / 4, blk, 0, stream>>>(
        row_ptr, colidx, lg_src, e_lg, lgmax, h1, h2, e_g, gden, g_dst, outp, E);
}

// Round 5
// 1412.260 us; speedup vs baseline: 1.1150x; 1.1150x over previous
//
#include <hip/hip_runtime.h>
#include <math.h>

#define LRELU(x) ((x) > 0.0f ? (x) : 0.01f * (x))

typedef __attribute__((ext_vector_type(8))) short short8;
typedef __attribute__((ext_vector_type(4))) float f32x4;

__device__ __forceinline__ unsigned fenc(float f) {
    unsigned u = __float_as_uint(f);
    return (u & 0x80000000u) ? ~u : (u | 0x80000000u);
}
__device__ __forceinline__ float fdec(unsigned u) {
    return __uint_as_float((u & 0x80000000u) ? (u & 0x7FFFFFFFu) : ~u);
}
__device__ __forceinline__ unsigned short f2bf(float f) {
    unsigned u = __float_as_uint(f);
    u += 0x7FFFu + ((u >> 16) & 1u);
    return (unsigned short)(u >> 16);
}
__device__ __forceinline__ float bf2f(unsigned short b) {
    return __uint_as_float(((unsigned)b) << 16);
}
__device__ __forceinline__ ushort4 cvt4(float4 v) {
    ushort4 p;
    p.x = f2bf(v.x); p.y = f2bf(v.y); p.z = f2bf(v.z); p.w = f2bf(v.w);
    return p;
}

// ---- all 8 weight matrices -> one contiguous bf16 arena, single launch ----
__global__ __launch_bounds__(256) void wcvt_k(
    const float* __restrict__ s0, const float* __restrict__ s1,
    const float* __restrict__ s2, const float* __restrict__ s3,
    const float* __restrict__ s4, const float* __restrict__ s5,
    const float* __restrict__ s6, const float* __restrict__ s7,
    unsigned short* __restrict__ dst)
{
    long long e = ((long long)blockIdx.x * 256 + threadIdx.x) * 4;
    if (e >= 327680) return;
    int c = (int)(e >> 15);
    const float* s;
    long long off = e & 32767;
    switch (c) {
        case 0: s = s0; break;
        case 1: s = s1; break;
        case 2: s = s2; break;
        case 3: s = s3; break;
        case 4: s = s4; break;
        case 5: s = s5; break;
        case 6: s = s6; break;
        case 7: s = s6; off += 32768; break;
        case 8: s = s7; break;
        default: s = s7; off += 32768; break;
    }
    float4 v = *(const float4*)&s[off];
    *(ushort4*)&dst[e] = cvt4(v);
}

// ---- fp32 -> bf16 streaming convert (m_feats) ----
__global__ __launch_bounds__(256) void cvt1_k(
    const float* __restrict__ in, unsigned short* __restrict__ out, int n4)
{
    int stride = gridDim.x * 256;
    for (int u = blockIdx.x * 256 + threadIdx.x; u < n4; u += stride) {
        float4 v = *(const float4*)&in[(size_t)u * 4];
        *(ushort4*)&out[(size_t)u * 4] = cvt4(v);
    }
}

// stage a 64-row x 128-col A tile into smem (coalesced, issue-all-then-write).
__device__ __forceinline__ void stage_A128(
    unsigned short* __restrict__ smem, const void* __restrict__ Av, int is_bf16,
    int row0, int M, int tid, int col_off, int stride)
{
    if (is_bf16) {
        const unsigned short* A = (const unsigned short*)Av;
        short8 v[4];
#pragma unroll
        for (int k = 0; k < 4; ++k) {
            int j = tid + k * 256;
            int r = row0 + (j >> 4);
#pragma unroll
            for (int q = 0; q < 8; ++q) v[k][q] = 0;
            if (r < M) v[k] = *(const short8*)&A[(size_t)r * 128 + (j & 15) * 8];
        }
#pragma unroll
        for (int k = 0; k < 4; ++k) {
            int j = tid + k * 256;
            *(short8*)&smem[(j >> 4) * stride + col_off + (j & 15) * 8] = v[k];
        }
    } else {
        const float* A = (const float*)Av;
        float4 va[8];
#pragma unroll
        for (int k = 0; k < 8; ++k) {
            int i = tid + k * 256;
            int r = row0 + (i >> 5);
            va[k] = make_float4(0.f, 0.f, 0.f, 0.f);
            if (r < M) va[k] = *(const float4*)&A[(size_t)r * 128 + (i & 31) * 4];
        }
#pragma unroll
        for (int k = 0; k < 8; ++k) {
            int i = tid + k * 256;
            *(ushort4*)&smem[(i >> 5) * stride + col_off + (i & 31) * 4] = cvt4(va[k]);
        }
    }
}

// ============ MFMA GEMM: C[M,256](bf16) = A[M,128] @ Wbf[256,128]^T ============
// r1 structure: staged A (stride 136), unroll-1 ks loop w/ in-loop ds_read.
__global__ __launch_bounds__(256) void gemm128_mfma(
    const void* __restrict__ Av, int a_is_bf16,
    const unsigned short* __restrict__ Wbf,
    const float* __restrict__ biasf, unsigned short* __restrict__ Cout, int M)
{
    __shared__ __align__(16) unsigned short smem[64 * 264];
    const int row0 = blockIdx.x * 64;
    const int tid = threadIdx.x;
    const int wv = tid >> 6, lane = tid & 63;
    const int ln = lane & 15, quad = lane >> 4;

    stage_A128(smem, Av, a_is_bf16, row0, M, tid, 0, 136);
    __syncthreads();

    f32x4 acc[16];
#pragma unroll
    for (int t = 0; t < 16; ++t) acc[t] = (f32x4){0.f, 0.f, 0.f, 0.f};

#pragma unroll 1
    for (int ks = 0; ks < 4; ++ks) {
        short8 a = *(const short8*)&smem[(wv * 16 + ln) * 136 + ks * 32 + quad * 8];
#pragma unroll
        for (int t = 0; t < 16; ++t) {
            short8 b = *(const short8*)&Wbf[(size_t)(t * 16 + ln) * 128 + ks * 32 + quad * 8];
            acc[t] = __builtin_amdgcn_mfma_f32_16x16x32_bf16(a, b, acc[t], 0, 0, 0);
        }
    }
    __syncthreads();

#pragma unroll
    for (int t = 0; t < 16; ++t) {
        int col = t * 16 + ln;
        float bb = biasf ? biasf[col] : 0.0f;
#pragma unroll
        for (int rg = 0; rg < 4; ++rg)
            smem[(wv * 16 + quad * 4 + rg) * 264 + col] = f2bf(acc[t][rg] + bb);
    }
    __syncthreads();
#pragma unroll 1
    for (int i = tid; i < 2048; i += 256) {
        int row = i >> 5, c8 = (i & 31) * 8;
        int r = row0 + row;
        if (r < M) *(short8*)&Cout[(size_t)r * 256 + c8] = *(const short8*)&smem[row * 264 + c8];
    }
}

// ============ fused fij MFMA GEMM + attention score (r1 structure) ============
__global__ __launch_bounds__(256) void gemm_score_mfma(
    const void* __restrict__ Av, int a_is_bf16,
    const unsigned short* __restrict__ Wbf,
    const unsigned short* __restrict__ fni, const unsigned short* __restrict__ fnj,
    const float* __restrict__ bias, const float* __restrict__ attn,
    const int* __restrict__ src, const int* __restrict__ dst,
    float* __restrict__ ebuf, unsigned* __restrict__ smax, int M)
{
    __shared__ __align__(16) unsigned short smem[64 * 264];
    const int row0 = blockIdx.x * 64;
    const int tid = threadIdx.x;
    const int wv = tid >> 6, lane = tid & 63;
    const int ln = lane & 15, quad = lane >> 4;

    // early index load for this wave's 16 rows (lane k<16 holds row rbase+k; dup x4)
    const int myr = row0 + wv * 16 + ln;
    int msrc = 0, mdst = 0;
    if (myr < M) { msrc = src[myr]; mdst = dst[myr]; }

    stage_A128(smem, Av, a_is_bf16, row0, M, tid, 0, 136);
    __syncthreads();

    f32x4 acc[16];
#pragma unroll
    for (int t = 0; t < 16; ++t) acc[t] = (f32x4){0.f, 0.f, 0.f, 0.f};

#pragma unroll 1
    for (int ks = 0; ks < 4; ++ks) {
        short8 a = *(const short8*)&smem[(wv * 16 + ln) * 136 + ks * 32 + quad * 8];
#pragma unroll
        for (int t = 0; t < 16; ++t) {
            short8 b = *(const short8*)&Wbf[(size_t)(t * 16 + ln) * 128 + ks * 32 + quad * 8];
            acc[t] = __builtin_amdgcn_mfma_f32_16x16x32_bf16(a, b, acc[t], 0, 0, 0);
        }
    }
    __syncthreads();  // all waves done reading A-stage before stash overwrites it

    const int c4 = lane * 4;                    // this lane's 4 columns
    const float4 bias4 = *(const float4*)&bias[c4];
    const float4 attn4 = *(const float4*)&attn[c4];

    // issue ALL 32 gathers now; they land while we stash fij to LDS
    ushort4 pu[16], pv[16];
#pragma unroll
    for (int j = 0; j < 16; ++j) {
        int s_ = __shfl(msrc, j, 16);
        int d_ = __shfl(mdst, j, 16);
        pu[j] = *(const ushort4*)&fni[(size_t)s_ * 256 + c4];
        pv[j] = *(const ushort4*)&fnj[(size_t)d_ * 256 + c4];
    }

    // stash fij (bf16) row-major; wave wv owns rows [wv*16, wv*16+16)
#pragma unroll
    for (int t = 0; t < 16; ++t) {
        int col = t * 16 + ln;
#pragma unroll
        for (int rg = 0; rg < 4; ++rg)
            smem[(wv * 16 + quad * 4 + rg) * 264 + col] = f2bf(acc[t][rg]);
    }
    // NO block barrier: each wave reads only its own rows
    asm volatile("" ::: "memory");

#pragma unroll
    for (int i = 0; i < 16; ++i) {
        int rr = wv * 16 + i;
        int r = row0 + rr;
        if (r >= M) continue;
        int dIdx = __shfl(mdst, i, 16);
        ushort4 f4 = *(const ushort4*)&smem[rr * 264 + c4];
        float v0 = bf2f(f4.x) + bf2f(pu[i].x) + bf2f(pv[i].x) + bias4.x;
        float v1 = bf2f(f4.y) + bf2f(pu[i].y) + bf2f(pv[i].y) + bias4.y;
        float v2 = bf2f(f4.z) + bf2f(pu[i].z) + bf2f(pv[i].z) + bias4.z;
        float v3 = bf2f(f4.w) + bf2f(pu[i].w) + bf2f(pv[i].w) + bias4.w;
        float p = LRELU(v0) * attn4.x + LRELU(v1) * attn4.y
                + LRELU(v2) * attn4.z + LRELU(v3) * attn4.w;
        // reduce across the 16 lanes of this quad (head = quad)
        p += __shfl_xor(p, 1, 64);
        p += __shfl_xor(p, 2, 64);
        p += __shfl_xor(p, 4, 64);
        p += __shfl_xor(p, 8, 64);
        if (ln == 0) {
            ebuf[(size_t)r * 4 + quad] = p;
            atomicMax(&smax[(size_t)dIdx * 4 + quad], fenc(p));
        }
    }
}

// ============ K=256 MFMA GEMM for h1 (mode 0) / h2 (mode 1) — r1 structure ============
__global__ __launch_bounds__(256) void gemm256_mfma(
    const void* __restrict__ Mv, int m_is_bf16,
    const unsigned short* __restrict__ Aux, const float* __restrict__ lf,
    const int* __restrict__ gsrc, const int* __restrict__ gdst,
    const unsigned short* __restrict__ Wbf, const float* __restrict__ biasf,
    unsigned short* __restrict__ Cout, int M, int mode)
{
    __shared__ __align__(16) unsigned short smem[64 * 264];
    const int row0 = blockIdx.x * 64;
    const int tid = threadIdx.x;
    const int wv = tid >> 6, lane = tid & 63;
    const int ln = lane & 15, quad = lane >> 4;

    if (mode == 0) {
        stage_A128(smem, Mv, m_is_bf16, row0, M, tid, 0, 264);
        stage_A128(smem, Aux, 1, row0, M, tid, 128, 264);
    } else {
        // cols 0..127: l_feats[src]+l_feats[dst] (index-prefetched)
        int is[8], id[8];
#pragma unroll
        for (int k = 0; k < 8; ++k) {
            int i = tid + k * 256;
            int r = row0 + (i >> 5);
            is[k] = (r < M) ? gsrc[r] : 0;
            id[k] = (r < M) ? gdst[r] : 0;
        }
        float4 va[8], vb2[8];
#pragma unroll
        for (int k = 0; k < 8; ++k) {
            int i = tid + k * 256;
            int c4i = (i & 31) * 4;
            va[k]  = *(const float4*)&lf[(size_t)is[k] * 128 + c4i];
            vb2[k] = *(const float4*)&lf[(size_t)id[k] * 128 + c4i];
        }
#pragma unroll
        for (int k = 0; k < 8; ++k) {
            int i = tid + k * 256;
            int r = row0 + (i >> 5);
            int c4i = (i & 31) * 4;
            float4 v = make_float4(va[k].x + vb2[k].x, va[k].y + vb2[k].y,
                                   va[k].z + vb2[k].z, va[k].w + vb2[k].w);
            if (r >= M) v = make_float4(0.f, 0.f, 0.f, 0.f);
            *(ushort4*)&smem[(i >> 5) * 264 + c4i] = cvt4(v);
        }
        // cols 128..255: m_feats
        stage_A128(smem, Mv, m_is_bf16, row0, M, tid, 128, 264);
    }
    __syncthreads();

    f32x4 acc[16];
#pragma unroll
    for (int t = 0; t < 16; ++t) acc[t] = (f32x4){0.f, 0.f, 0.f, 0.f};

#pragma unroll 1
    for (int ks = 0; ks < 8; ++ks) {
        short8 a = *(const short8*)&smem[(wv * 16 + ln) * 264 + ks * 32 + quad * 8];
#pragma unroll
        for (int t = 0; t < 16; ++t) {
            short8 b = *(const short8*)&Wbf[(size_t)(t * 16 + ln) * 256 + ks * 32 + quad * 8];
            acc[t] = __builtin_amdgcn_mfma_f32_16x16x32_bf16(a, b, acc[t], 0, 0, 0);
        }
    }
    __syncthreads();

#pragma unroll
    for (int t = 0; t < 16; ++t) {
        int col = t * 16 + ln;
        float bb = biasf[col];
#pragma unroll
        for (int rg = 0; rg < 4; ++rg)
            smem[(wv * 16 + quad * 4 + rg) * 264 + col] = f2bf(acc[t][rg] + bb);
    }
    __syncthreads();
#pragma unroll 1
    for (int i = tid; i < 2048; i += 256) {
        int row = i >> 5, c8 = (i & 31) * 8;
        int r = row0 + row;
        if (r < M) *(short8*)&Cout[(size_t)r * 256 + c8] = *(const short8*)&smem[row * 264 + c8];
    }
}

// ---------------- softmax pass 2 (g branch): exp(e-max), atomic denom ----------------
__global__ __launch_bounds__(256) void edge_exp(
    float* __restrict__ ebuf, const unsigned* __restrict__ smax,
    float* __restrict__ sden, const int* __restrict__ dst, int nE)
{
    int i = blockIdx.x * 256 + threadIdx.x;
    if (i >= nE * 4) return;
    int e = i >> 2, h = i & 3;
    int d = dst[e];
    float m = fdec(smax[(size_t)d * 4 + h]);
    float ex = expf(ebuf[i] - m);
    ebuf[i] = ex;
    atomicAdd(&sden[(size_t)d * 4 + h], ex);
}

// ================= CSR build over lg_dst =================
__global__ __launch_bounds__(256) void count_k(
    const int* __restrict__ dst, int* __restrict__ cnt, int n)
{
    int i = blockIdx.x * 256 + threadIdx.x;
    if (i < n) atomicAdd(&cnt[dst[i]], 1);
}

__global__ __launch_bounds__(256) void scan1(
    const int* __restrict__ cnt, int* __restrict__ excl, int* __restrict__ bsum, int n)
{
    __shared__ int sd[256];
    int tid = threadIdx.x;
    int i = blockIdx.x * 256 + tid;
    int v = (i < n) ? cnt[i] : 0;
    sd[tid] = v;
    __syncthreads();
    for (int off2 = 1; off2 < 256; off2 <<= 1) {
        int t = (tid >= off2) ? sd[tid - off2] : 0;
        __syncthreads();
        sd[tid] += t;
        __syncthreads();
    }
    if (i < n) excl[i] = sd[tid] - v;
    if (tid == 255) bsum[blockIdx.x] = sd[255];
}

__global__ __launch_bounds__(1024) void scan2(int* __restrict__ bsum, int nb)
{
    __shared__ int sd[1024];
    int tid = threadIdx.x;
    int v = (tid < nb) ? bsum[tid] : 0;
    sd[tid] = v;
    __syncthreads();
    for (int off2 = 1; off2 < 1024; off2 <<= 1) {
        int t = (tid >= off2) ? sd[tid - off2] : 0;
        __syncthreads();
        sd[tid] += t;
        __syncthreads();
    }
    if (tid < nb) bsum[tid] = sd[tid] - v;  // exclusive
}

__global__ __launch_bounds__(256) void scan3(
    int* __restrict__ excl, const int* __restrict__ bsum, int n, int total)
{
    int i = blockIdx.x * 256 + threadIdx.x;
    if (i < n) excl[i] += bsum[i >> 8];
    if (i == 0) excl[n] = total;
}

__global__ __launch_bounds__(256) void fill_k(
    const int* __restrict__ dst, const int* __restrict__ row_ptr,
    int* __restrict__ cursor, int* __restrict__ colidx, int n)
{
    int i = blockIdx.x * 256 + threadIdx.x;
    if (i >= n) return;
    int d = dst[i];
    int p = atomicAdd(&cursor[d], 1);
    colidx[row_ptr[d] + p] = i;
}

// ---------------- CSR mean-gather of x_feats onto lg_dst (bf16 out) ----------------
__global__ __launch_bounds__(256) void agg_gather(
    const int* __restrict__ row_ptr, const int* __restrict__ colidx,
    const float* __restrict__ x, unsigned short* __restrict__ aggbf, int nE)
{
    const int lane = threadIdx.x & 63;
    const int d = blockIdx.x * 4 + (threadIdx.x >> 6);
    if (d >= nE) return;
    int b = row_ptr[d], en = row_ptr[d + 1];
    float s0 = 0.f, s1 = 0.f;
    for (int k = b; k < en; ++k) {
        int e = colidx[k];
        float2 v = *(const float2*)&x[(size_t)e * 128 + lane * 2];
        s0 += v.x; s1 += v.y;
    }
    float c = fmaxf((float)(en - b), 1.0f);
    ushort2 o;
    o.x = f2bf(s0 / c); o.y = f2bf(s1 / c);
    *(ushort2*)&aggbf[(size_t)d * 128 + lane * 2] = o;
}

// ---------------- final: lg-softmax (max precomputed) + weighted gather + epilogue ----------------
__global__ __launch_bounds__(256) void final_agg(
    const int* __restrict__ row_ptr, const int* __restrict__ colidx,
    const int* __restrict__ lg_src, const float* __restrict__ e_lg,
    const unsigned* __restrict__ lgmax,
    const unsigned short* __restrict__ h1, const unsigned short* __restrict__ h2,
    const float* __restrict__ e_g, const float* __restrict__ gden,
    const int* __restrict__ g_dst, float* __restrict__ out, int nE)
{
    const int lane = threadIdx.x & 63;
    const int d = blockIdx.x * 4 + (threadIdx.x >> 6);
    if (d >= nE) return;
    int b = row_ptr[d], en = row_ptr[d + 1];

    uint4 mu = *(const uint4*)&lgmax[(size_t)d * 4];
    float mx0 = fdec(mu.x), mx1 = fdec(mu.y), mx2 = fdec(mu.z), mx3 = fdec(mu.w);

    float den0 = 0.f, den1 = 0.f, den2 = 0.f, den3 = 0.f;
    float a10 = 0.f, a11 = 0.f, a12 = 0.f, a13 = 0.f;
    float a20 = 0.f, a21 = 0.f, a22 = 0.f, a23 = 0.f;
    for (int k = b; k < en; ++k) {
        int e = colidx[k];
        float4 sc = *(const float4*)&e_lg[(size_t)e * 4];
        float w0 = expf(sc.x - mx0), w1 = expf(sc.y - mx1);
        float w2 = expf(sc.z - mx2), w3 = expf(sc.w - mx3);
        den0 += w0; den1 += w1; den2 += w2; den3 += w3;
        int s = lg_src[e];
        const unsigned short* p1 = &h1[(size_t)s * 256 + lane];
        const unsigned short* p2 = &h2[(size_t)s * 256 + lane];
        a10 += bf2f(p1[0])   * w0;
        a11 += bf2f(p1[64])  * w1;
        a12 += bf2f(p1[128]) * w2;
        a13 += bf2f(p1[192]) * w3;
        a20 += bf2f(p2[0]);
        a21 += bf2f(p2[64]);
        a22 += bf2f(p2[128]);
        a23 += bf2f(p2[192]);
    }
    float o = 0.f;
    if (en > b) {
        float v0 = a10 / den0, v1 = a11 / den1, v2 = a12 / den2, v3 = a13 / den3;
        o += LRELU(v0) + LRELU(v1) + LRELU(v2) + LRELU(v3);
    }
    int gd = g_dst[d];
    float g0 = e_g[(size_t)d * 4 + 0] / gden[(size_t)gd * 4 + 0] * a20;
    float g1 = e_g[(size_t)d * 4 + 1] / gden[(size_t)gd * 4 + 1] * a21;
    float g2 = e_g[(size_t)d * 4 + 2] / gden[(size_t)gd * 4 + 2] * a22;
    float g3 = e_g[(size_t)d * 4 + 3] / gden[(size_t)gd * 4 + 3] * a23;
    o += LRELU(g0) + LRELU(g1) + LRELU(g2) + LRELU(g3);
    out[(size_t)d * 64 + lane] = o;
}

extern "C" void kernel_launch(void* const* d_in, const int* in_sizes, int n_in,
                              void* d_out, int out_size, void* d_ws, size_t ws_size,
                              hipStream_t stream)
{
    const float* l_feats   = (const float*)d_in[0];
    const float* m_feats   = (const float*)d_in[1];
    const float* x_feats   = (const float*)d_in[2];
    const int*   g_src     = (const int*)d_in[3];
    const int*   g_dst     = (const int*)d_in[4];
    const int*   lg_src    = (const int*)d_in[5];
    const int*   lg_dst    = (const int*)d_in[6];
    const float* W_lg_node = (const float*)d_in[7];
    const float* b_lg_node = (const float*)d_in[8];
    const float* W_lg_ni   = (const float*)d_in[9];
    const float* W_lg_fij  = (const float*)d_in[10];
    const float* W_lg_nj   = (const float*)d_in[11];
    const float* lg_attn   = (const float*)d_in[12];
    const float* bias_lg   = (const float*)d_in[13];
    const float* W_g_node  = (const float*)d_in[14];
    const float* b_g_node  = (const float*)d_in[15];
    const float* W_g_ni    = (const float*)d_in[16];
    const float* W_g_fij   = (const float*)d_in[17];
    const float* W_g_nj    = (const float*)d_in[18];
    const float* g_attn    = (const float*)d_in[19];
    const float* bias_g    = (const float*)d_in[20];

    const int N  = in_sizes[0] / 128;
    const int E  = in_sizes[3];
    const int E2 = in_sizes[5];

    float* ws = (float*)d_ws;
    size_t off = 0;
    auto alloc = [&](size_t n) { float* p = ws + off; off += n; return p; };

    // bf16 weights arena (ushort offsets within a float-slot arena)
    unsigned short* wbuf = (unsigned short*)alloc(163840);
    unsigned short* wgni_bf    = wbuf;
    unsigned short* wgnj_bf    = wbuf + 32768;
    unsigned short* wlgni_bf   = wbuf + 65536;
    unsigned short* wlgnj_bf   = wbuf + 98304;
    unsigned short* wlgfij_bf  = wbuf + 131072;
    unsigned short* wgfij_bf   = wbuf + 163840;
    unsigned short* wlgnode_bf = wbuf + 196608;
    unsigned short* wgnode_bf  = wbuf + 262144;

    unsigned short* ni_lg = (unsigned short*)alloc((size_t)E * 128);  // [E,256] bf16 -> h1
    unsigned short* nj_lg = (unsigned short*)alloc((size_t)E * 128);  // [E,256] bf16 -> h2
    unsigned short* gni   = (unsigned short*)alloc((size_t)N * 128);
    unsigned short* gnj   = (unsigned short*)alloc((size_t)N * 128);
    unsigned short* aggbf = (unsigned short*)alloc((size_t)E * 64);   // [E,128] bf16
    float* e_lg  = alloc((size_t)E2 * 4);                             // raw lg scores
    float* e_g   = alloc((size_t)E * 4);                              // raw -> exp g scores
    unsigned* gmax = (unsigned*)alloc((size_t)N * 4);
    float* gden  = alloc((size_t)N * 4);
    unsigned* lgmax = (unsigned*)alloc((size_t)E * 4);                // lg segment max (fenc)
    int* row_ptr = (int*)alloc((size_t)E + 4);
    int* colidx  = (int*)alloc((size_t)E2);
    int* cnt     = (int*)alloc((size_t)E);
    int* cursor  = (int*)alloc((size_t)E);
    int* bsum    = (int*)alloc(1024);

    // mbf allocated LAST and only if it fits in the workspace (ws overflow guard)
    const int use_mbf = ((off + (size_t)E * 64) * sizeof(float) <= ws_size) ? 1 : 0;
    unsigned short* mbf = use_mbf ? (unsigned short*)alloc((size_t)E * 64) : nullptr;
    const void* mA = use_mbf ? (const void*)mbf : (const void*)m_feats;

    unsigned short* h1 = ni_lg;
    unsigned short* h2 = nj_lg;

    (void)n_in; (void)out_size;
    float* outp = (float*)d_out;
    dim3 blk(256);

    hipMemsetAsync(cnt,    0, (size_t)E * 4, stream);
    hipMemsetAsync(cursor, 0, (size_t)E * 4, stream);
    hipMemsetAsync(gmax,   0, (size_t)N * 4 * 4, stream);
    hipMemsetAsync(gden,   0, (size_t)N * 4 * 4, stream);
    hipMemsetAsync(lgmax,  0, (size_t)E * 4 * 4, stream);

    // all weights -> bf16 arena (one launch); m_feats -> bf16 if space permits
    wcvt_k<<<320, blk, 0, stream>>>(W_g_ni, W_g_nj, W_lg_ni, W_lg_nj,
                                    W_lg_fij, W_g_fij, W_lg_node, W_g_node, wbuf);
    if (use_mbf)
        cvt1_k<<<2048, blk, 0, stream>>>(m_feats, mbf, E * 32);

    // CSR over lg_dst
    const int nb = (E + 255) / 256;
    count_k<<<(E2 + 255) / 256, blk, 0, stream>>>(lg_dst, cnt, E2);
    scan1<<<nb, blk, 0, stream>>>(cnt, row_ptr, bsum, E);
    scan2<<<1, 1024, 0, stream>>>(bsum, nb);
    scan3<<<nb, blk, 0, stream>>>(row_ptr, bsum, E, E2);
    fill_k<<<(E2 + 255) / 256, blk, 0, stream>>>(lg_dst, row_ptr, cursor, colidx, E2);

    // projection GEMMs (K=128 -> 256 cols, bf16 out) — r1 structure
    gemm128_mfma<<<(N + 63) / 64, blk, 0, stream>>>(l_feats, 0, wgni_bf, nullptr, gni, N);
    gemm128_mfma<<<(N + 63) / 64, blk, 0, stream>>>(l_feats, 0, wgnj_bf, nullptr, gnj, N);
    gemm128_mfma<<<(E + 63) / 64, blk, 0, stream>>>(mA, use_mbf, wlgni_bf, nullptr, ni_lg, E);
    gemm128_mfma<<<(E + 63) / 64, blk, 0, stream>>>(mA, use_mbf, wlgnj_bf, nullptr, nj_lg, E);

    // fused fij GEMM + raw scores (+ segment max for both branches)
    gemm_score_mfma<<<(E2 + 63) / 64, blk, 0, stream>>>(
        x_feats, 0, wlgfij_bf, ni_lg, nj_lg, bias_lg, lg_attn, lg_src, lg_dst,
        e_lg, lgmax, E2);
    gemm_score_mfma<<<(E + 63) / 64, blk, 0, stream>>>(
        mA, use_mbf, wgfij_bf, gni, gnj, bias_g, g_attn, g_src, g_dst,
        e_g, gmax, E);

    // g softmax pass 2 (exp + denom)
    edge_exp<<<(unsigned)(((long long)E * 4 + 255) / 256), blk, 0, stream>>>(e_g, gmax, gden, g_dst, E);

    // CSR mean-gather of x_feats -> aggbf (fp32 input for accuracy)
    agg_gather<<<(E + 3) / 4, blk, 0, stream>>>(row_ptr, colidx, x_feats, aggbf, E);

    // node-update GEMMs (overwrite ni_lg/nj_lg -> h1/h2; safe after gemm_score)
    gemm256_mfma<<<(E + 63) / 64, blk, 0, stream>>>(
        mA, use_mbf, aggbf, nullptr, nullptr, nullptr, wlgnode_bf, b_lg_node, h1, E, 0);
    gemm256_mfma<<<(E + 63) / 64, blk, 0, stream>>>(
        mA, use_mbf, nullptr, l_feats, g_src, g_dst, wgnode_bf, b_g_node, h2, E, 1);

    // final: lg softmax (max precomputed) + weighted gathers + epilogue
    final_agg<<<(E + 3) / 4, blk, 0, stream>>>(
        row_ptr, colidx, lg_src, e_lg, lgmax, h1, h2, e_g, gden, g_dst, outp, E);
}